// Round 2
// baseline (5804.755 us; speedup 1.0000x reference)
//
#include <hip/hip_runtime.h>
#include <math.h>

#define N_IN   65536
#define N_UP   262144
#define N_OUT  131072
#define C_IN   128
#define C_OUT  64
#define K1     27
#define K2     27
#define K3     16
#define M1     65536
#define M2     131072
#define M3     131072
#define EPSV   1e-6f

// One wave per gathered row r in [0, K*M). Lane = output channel.
// X fp32 [*, CIN]; W fp32 [K, CIN, 64]; scatter via fp32 atomics.
template <int CIN, int MSHIFT>
__global__ __launch_bounds__(256) void conv_scatter(
    const float* __restrict__ X, const float* __restrict__ W,
    const int* __restrict__ kin, const int* __restrict__ kout,
    float* __restrict__ outp)
{
    __shared__ float xs[4][CIN];
    const int wid  = threadIdx.x >> 6;
    const int lane = threadIdx.x & 63;
    const int r = blockIdx.x * 4 + wid;           // grid is an exact multiple of 4
    const int k = r >> MSHIFT;
    const int src = kin[r];
    const int dst = kout[r];

    const float* xr = X + (size_t)src * CIN;
    xs[wid][lane] = xr[lane];
    if (CIN == 128) xs[wid][lane + 64] = xr[lane + 64];
    __syncthreads();

    const float* wk = W + (size_t)k * (CIN * 64) + lane;
    float acc = 0.f;
#pragma unroll 8
    for (int i = 0; i < CIN; ++i)
        acc = fmaf(xs[wid][i], wk[i * 64], acc);

    atomicAdd(outp + (size_t)dst * 64 + lane, acc);
}

// Per-channel sum / sumsq partials -> atomics into stats[0:64]=sum, [64:128]=sumsq
__global__ __launch_bounds__(256) void stats_kernel(
    const float* __restrict__ x, int nrows, float* __restrict__ stats)
{
    const int c  = threadIdx.x & 63;
    const int rw = threadIdx.x >> 6;
    float s = 0.f, s2 = 0.f;
    for (int r = blockIdx.x * 4 + rw; r < nrows; r += gridDim.x * 4) {
        float v = x[(size_t)r * 64 + c];
        s += v;
        s2 = fmaf(v, v, s2);
    }
    atomicAdd(stats + c, s);
    atomicAdd(stats + 64 + c, s2);
}

// stats[128+c]=mean, stats[192+c]=rsqrt(var+eps)
__global__ void finalize_stats(float* stats, float inv_n)
{
    const int c = threadIdx.x;   // 64 threads
    float mu  = stats[c] * inv_n;
    float var = stats[64 + c] * inv_n - mu * mu;
    stats[128 + c] = mu;
    stats[192 + c] = rsqrtf(var + EPSV);
}

// x = elu((x-mu)*scale) (+ fp32 encoder skip if enc != null), in place.
__global__ __launch_bounds__(256) void norm_elu(
    float* __restrict__ x, const float* __restrict__ stats,
    const float* __restrict__ enc)
{
    const int i = blockIdx.x * 256 + threadIdx.x;
    const int c = i & 63;
    float v = (x[i] - stats[128 + c]) * stats[192 + c];
    v = (v > 0.f) ? v : expm1f(v);
    if (enc) v += enc[i];
    x[i] = v;
}

// Final: normalize+elu, pruning dot, keep mask, fp32 outputs.
__global__ __launch_bounds__(256) void final_kernel(
    const float* __restrict__ x, const float* __restrict__ stats,
    const float* __restrict__ Wp, const float* __restrict__ bp,
    float* __restrict__ outp)
{
    const int lane = threadIdx.x & 63;
    const int wid  = threadIdx.x >> 6;
    const int row  = blockIdx.x * 4 + wid;

    float v = (x[(size_t)row * 64 + lane] - stats[128 + lane]) * stats[192 + lane];
    v = (v > 0.f) ? v : expm1f(v);

    float p = v * Wp[lane];
#pragma unroll
    for (int m = 1; m < 64; m <<= 1)
        p += __shfl_xor(p, m, 64);
    p += bp[0];

    const bool keep = p > 0.0f;
    outp[(size_t)row * 64 + lane] = keep ? v : 0.f;
    if (lane == 0)
        outp[(size_t)N_OUT * 64 + row] = keep ? 1.f : 0.f;
}

extern "C" void kernel_launch(void* const* d_in, const int* in_sizes, int n_in,
                              void* d_out, int out_size, void* d_ws, size_t ws_size,
                              hipStream_t stream)
{
    const float* in_feats = (const float*)d_in[0];   // [65536,128] f32
    const float* enc      = (const float*)d_in[1];   // [262144,64] f32
    const float* W1       = (const float*)d_in[2];   // [27,128,64] f32
    const float* W2       = (const float*)d_in[3];   // [27,64,64]  f32
    const float* W3       = (const float*)d_in[4];   // [16,64,64]  f32
    const float* Wp       = (const float*)d_in[5];   // [64,1] f32
    const float* bp       = (const float*)d_in[6];   // [1] f32
    const int* kin1  = (const int*)d_in[7];
    const int* kout1 = (const int*)d_in[8];
    const int* kin2  = (const int*)d_in[9];
    const int* kout2 = (const int*)d_in[10];
    const int* kin3  = (const int*)d_in[11];
    const int* kout3 = (const int*)d_in[12];
    float* outp = (float*)d_out;

    char* ws = (char*)d_ws;
    float* up_a   = (float*)ws;                         // 64 MB  [262144,64] f32
    float* up_b   = (float*)(ws + 67108864);            // 64 MB  [262144,64] f32
    float* out3   = up_a;                               // 32 MB reuse after conv2
    float* statsA = (float*)(ws + 134217728);           // 256 f32 each
    float* statsB = statsA + 256;
    float* statsC = statsA + 512;

    // Zero accumulators + stats (ws is poisoned 0xAA before every launch)
    hipMemsetAsync(up_a, 0, (size_t)N_UP * 64 * 4, stream);
    hipMemsetAsync(up_b, 0, (size_t)N_UP * 64 * 4, stream);
    hipMemsetAsync(statsA, 0, 3 * 256 * 4, stream);

    // ---- dec_block_1a: conv-transpose (gather input_feats, scatter to up_a)
    conv_scatter<128, 16><<<(K1 * M1) / 4, 256, 0, stream>>>(
        in_feats, W1, kin1, kout1, up_a);
    stats_kernel<<<2048, 256, 0, stream>>>(up_a, N_UP, statsA);
    finalize_stats<<<1, 64, 0, stream>>>(statsA, 1.f / N_UP);
    norm_elu<<<(N_UP * 64) / 256, 256, 0, stream>>>(up_a, statsA, nullptr);

    // ---- dec_block_1b: conv 3x3x3 (up_a -> up_b)
    conv_scatter<64, 17><<<(K2 * M2) / 4, 256, 0, stream>>>(
        up_a, W2, kin2, kout2, up_b);
    stats_kernel<<<2048, 256, 0, stream>>>(up_b, N_UP, statsB);
    finalize_stats<<<1, 64, 0, stream>>>(statsB, 1.f / N_UP);
    norm_elu<<<(N_UP * 64) / 256, 256, 0, stream>>>(up_b, statsB, enc);  // + skip

    // ---- dec_block_2: conv k=2 (up_b -> out3), out3 reuses up_a storage
    hipMemsetAsync(out3, 0, (size_t)N_OUT * 64 * 4, stream);
    conv_scatter<64, 17><<<(K3 * M3) / 4, 256, 0, stream>>>(
        up_b, W3, kin3, kout3, out3);
    stats_kernel<<<2048, 256, 0, stream>>>(out3, N_OUT, statsC);
    finalize_stats<<<1, 64, 0, stream>>>(statsC, 1.f / N_OUT);

    // ---- pruning head + fp32 outputs
    final_kernel<<<N_OUT / 4, 256, 0, stream>>>(out3, statsC, Wp, bp, outp);
}

// Round 3
// 2770.391 us; speedup vs baseline: 2.0953x; 2.0953x over previous
//
#include <hip/hip_runtime.h>
#include <math.h>

#define N_IN   65536
#define N_UP   262144
#define N_OUT  131072
#define C_IN   128
#define C_OUT  64
#define K1     27
#define K2     27
#define K3     16
#define M1     65536
#define M2     131072
#define M3     131072
#define EPSV   1e-6f
#define WPK    256          // waves per kernel-offset
#define WPK_SHIFT 8

// One wave owns one kernel-offset k and R consecutive pairs of it.
// Weight column W[k][:, lane] held in VGPRs; gathered x-row read via
// wave-uniform scalar loads; one fp32 atomic per output element.
template <int CIN, int R>
__global__ __launch_bounds__(256) void conv_scatter_reg(
    const float* __restrict__ X, const float* __restrict__ W,
    const int* __restrict__ kin, const int* __restrict__ kout,
    float* __restrict__ outp)
{
    const int lane = threadIdx.x & 63;
    const int wave = blockIdx.x * 4 + (threadIdx.x >> 6);
    const int k    = wave >> WPK_SHIFT;
    const int widx = wave & (WPK - 1);

    // load weight column into registers (once per wave, L2-hot)
    float wreg[CIN];
    {
        const float* wk = W + (size_t)k * (CIN * 64) + lane;
#pragma unroll
        for (int i = 0; i < CIN; ++i) wreg[i] = wk[i * 64];
    }

    const long long rbase = (long long)k * (WPK * R) + (long long)widx * R;
    const int* kin_p  = kin + rbase;
    const int* kout_p = kout + rbase;

#pragma unroll 2
    for (int rr = 0; rr < R; ++rr) {
        const int src = __builtin_amdgcn_readfirstlane(kin_p[rr]);
        const int dst = __builtin_amdgcn_readfirstlane(kout_p[rr]);
        const float* xr = X + (size_t)src * CIN;   // uniform -> s_load
        float a0 = 0.f, a1 = 0.f, a2 = 0.f, a3 = 0.f;
#pragma unroll
        for (int i = 0; i < CIN; i += 4) {
            a0 = fmaf(xr[i + 0], wreg[i + 0], a0);
            a1 = fmaf(xr[i + 1], wreg[i + 1], a1);
            a2 = fmaf(xr[i + 2], wreg[i + 2], a2);
            a3 = fmaf(xr[i + 3], wreg[i + 3], a3);
        }
        atomicAdd(outp + (size_t)dst * 64 + lane, (a0 + a1) + (a2 + a3));
    }
}

// Per-channel sum/sumsq; LDS reduce across the block's 4 waves, then atomics.
__global__ __launch_bounds__(256) void stats_kernel(
    const float* __restrict__ x, int nrows, float* __restrict__ stats)
{
    __shared__ float sh[2][4][64];
    const int c  = threadIdx.x & 63;
    const int rw = threadIdx.x >> 6;
    float s = 0.f, s2 = 0.f;
    for (int r = blockIdx.x * 4 + rw; r < nrows; r += gridDim.x * 4) {
        float v = x[(size_t)r * 64 + c];
        s += v;
        s2 = fmaf(v, v, s2);
    }
    sh[0][rw][c] = s;
    sh[1][rw][c] = s2;
    __syncthreads();
    if (rw == 0) {
        s  = (sh[0][0][c] + sh[0][1][c]) + (sh[0][2][c] + sh[0][3][c]);
        s2 = (sh[1][0][c] + sh[1][1][c]) + (sh[1][2][c] + sh[1][3][c]);
        atomicAdd(stats + c, s);
        atomicAdd(stats + 64 + c, s2);
    }
}

// stats[128+c]=mean, stats[192+c]=rsqrt(var+eps)
__global__ void finalize_stats(float* stats, float inv_n)
{
    const int c = threadIdx.x;   // 64 threads
    float mu  = stats[c] * inv_n;
    float var = stats[64 + c] * inv_n - mu * mu;
    stats[128 + c] = mu;
    stats[192 + c] = rsqrtf(var + EPSV);
}

// x = elu((x-mu)*scale) (+ fp32 encoder skip if enc != null), in place.
__global__ __launch_bounds__(256) void norm_elu(
    float* __restrict__ x, const float* __restrict__ stats,
    const float* __restrict__ enc)
{
    const int i = blockIdx.x * 256 + threadIdx.x;
    const int c = i & 63;
    float v = (x[i] - stats[128 + c]) * stats[192 + c];
    v = (v > 0.f) ? v : expm1f(v);
    if (enc) v += enc[i];
    x[i] = v;
}

// Final: normalize+elu, pruning dot, keep mask, fp32 outputs.
__global__ __launch_bounds__(256) void final_kernel(
    const float* __restrict__ x, const float* __restrict__ stats,
    const float* __restrict__ Wp, const float* __restrict__ bp,
    float* __restrict__ outp)
{
    const int lane = threadIdx.x & 63;
    const int wid  = threadIdx.x >> 6;
    const int row  = blockIdx.x * 4 + wid;

    float v = (x[(size_t)row * 64 + lane] - stats[128 + lane]) * stats[192 + lane];
    v = (v > 0.f) ? v : expm1f(v);

    float p = v * Wp[lane];
#pragma unroll
    for (int m = 1; m < 64; m <<= 1)
        p += __shfl_xor(p, m, 64);
    p += bp[0];

    const bool keep = p > 0.0f;
    outp[(size_t)row * 64 + lane] = keep ? v : 0.f;
    if (lane == 0)
        outp[(size_t)N_OUT * 64 + row] = keep ? 1.f : 0.f;
}

extern "C" void kernel_launch(void* const* d_in, const int* in_sizes, int n_in,
                              void* d_out, int out_size, void* d_ws, size_t ws_size,
                              hipStream_t stream)
{
    const float* in_feats = (const float*)d_in[0];   // [65536,128] f32
    const float* enc      = (const float*)d_in[1];   // [262144,64] f32
    const float* W1       = (const float*)d_in[2];   // [27,128,64] f32
    const float* W2       = (const float*)d_in[3];   // [27,64,64]  f32
    const float* W3       = (const float*)d_in[4];   // [16,64,64]  f32
    const float* Wp       = (const float*)d_in[5];   // [64,1] f32
    const float* bp       = (const float*)d_in[6];   // [1] f32
    const int* kin1  = (const int*)d_in[7];
    const int* kout1 = (const int*)d_in[8];
    const int* kin2  = (const int*)d_in[9];
    const int* kout2 = (const int*)d_in[10];
    const int* kin3  = (const int*)d_in[11];
    const int* kout3 = (const int*)d_in[12];
    float* outp = (float*)d_out;

    char* ws = (char*)d_ws;
    float* up_a   = (float*)ws;                         // 64 MB  [262144,64] f32
    float* up_b   = (float*)(ws + 67108864);            // 64 MB  [262144,64] f32
    float* out3   = up_a;                               // 32 MB reuse after conv2
    float* statsA = (float*)(ws + 134217728);           // 256 f32 each
    float* statsB = statsA + 256;
    float* statsC = statsA + 512;

    hipMemsetAsync(up_a, 0, (size_t)N_UP * 64 * 4, stream);
    hipMemsetAsync(up_b, 0, (size_t)N_UP * 64 * 4, stream);
    hipMemsetAsync(statsA, 0, 3 * 256 * 4, stream);

    // ---- dec_block_1a: conv-transpose (gather input_feats, scatter to up_a)
    conv_scatter_reg<128, M1 / WPK><<<(K1 * WPK) / 4, 256, 0, stream>>>(
        in_feats, W1, kin1, kout1, up_a);
    stats_kernel<<<512, 256, 0, stream>>>(up_a, N_UP, statsA);
    finalize_stats<<<1, 64, 0, stream>>>(statsA, 1.f / N_UP);
    norm_elu<<<(N_UP * 64) / 256, 256, 0, stream>>>(up_a, statsA, nullptr);

    // ---- dec_block_1b: conv 3x3x3 (up_a -> up_b)
    conv_scatter_reg<64, M2 / WPK><<<(K2 * WPK) / 4, 256, 0, stream>>>(
        up_a, W2, kin2, kout2, up_b);
    stats_kernel<<<512, 256, 0, stream>>>(up_b, N_UP, statsB);
    finalize_stats<<<1, 64, 0, stream>>>(statsB, 1.f / N_UP);
    norm_elu<<<(N_UP * 64) / 256, 256, 0, stream>>>(up_b, statsB, enc);  // + skip

    // ---- dec_block_2: conv k=2 (up_b -> out3), out3 reuses up_a storage
    hipMemsetAsync(out3, 0, (size_t)N_OUT * 64 * 4, stream);
    conv_scatter_reg<64, M3 / WPK><<<(K3 * WPK) / 4, 256, 0, stream>>>(
        up_b, W3, kin3, kout3, out3);
    stats_kernel<<<512, 256, 0, stream>>>(out3, N_OUT, statsC);
    finalize_stats<<<1, 64, 0, stream>>>(statsC, 1.f / N_OUT);

    // ---- pruning head + fp32 outputs
    final_kernel<<<N_OUT / 4, 256, 0, stream>>>(out3, statsC, Wp, bp, outp);
}

// Round 4
// 2505.066 us; speedup vs baseline: 2.3172x; 1.1059x over previous
//
#include <hip/hip_runtime.h>
#include <math.h>

#define N_IN   65536
#define N_UP   262144
#define N_OUT  131072
#define C_IN   128
#define C_OUT  64
#define K1     27
#define K2     27
#define K3     16
#define M1     65536
#define M2     131072
#define M3     131072
#define EPSV   1e-6f
#define WPK    256          // waves per kernel-offset
#define WPK_SHIFT 8

// Outer-product sparse conv: lane = gathered row. Each wave owns offset k and
// R = M/WPK rows, processed in batches of 64 (one row per lane).
//  - x rows: per-lane vector gathers (float4), double-buffered across k-chunks
//  - weights: wave-uniform -> scalar loads broadcast into FMA s-operand
//  - acc[64] fp32 per lane; scatter via LDS transpose -> row-contiguous atomics
template <int CIN, int MSHIFT>
__global__ __launch_bounds__(256) void conv_gemm(
    const float* __restrict__ X, const float* __restrict__ W,
    const int* __restrict__ kin, const int* __restrict__ kout,
    float* __restrict__ outp)
{
    __shared__ float lds_t[4][64][20];   // [wave][row][16 ch + pad], float4-aligned
    __shared__ int   lds_dst[4][64];

    const int lane = threadIdx.x & 63;
    const int wv   = threadIdx.x >> 6;
    const int wave = blockIdx.x * 4 + wv;
    const int k    = __builtin_amdgcn_readfirstlane(wave >> WPK_SHIFT);
    const int widx = wave & (WPK - 1);
    constexpr int R  = (1 << MSHIFT) / WPK;
    constexpr int NB = R / 64;
    constexpr int KC = CIN / 16;

    const float* Wk = W + (size_t)k * (CIN * 64);
    const int base = (k << MSHIFT) + widx * R;

    for (int b = 0; b < NB; ++b) {
        const int j   = base + b * 64 + lane;
        const int src = kin[j];
        const int dst = kout[j];
        lds_dst[wv][lane] = dst;

        const float4* xr = (const float4*)(X + (size_t)src * CIN);

        float acc[64];
#pragma unroll
        for (int c = 0; c < 64; ++c) acc[c] = 0.f;

        float4 xa0 = xr[0], xa1 = xr[1], xa2 = xr[2], xa3 = xr[3];

        for (int kc = 0; kc < KC; ++kc) {
            float4 xb0, xb1, xb2, xb3;
            if (kc + 1 < KC) {
                xb0 = xr[(kc + 1) * 4 + 0];
                xb1 = xr[(kc + 1) * 4 + 1];
                xb2 = xr[(kc + 1) * 4 + 2];
                xb3 = xr[(kc + 1) * 4 + 3];
            }
            float xs[16];
            xs[0]=xa0.x; xs[1]=xa0.y; xs[2]=xa0.z; xs[3]=xa0.w;
            xs[4]=xa1.x; xs[5]=xa1.y; xs[6]=xa1.z; xs[7]=xa1.w;
            xs[8]=xa2.x; xs[9]=xa2.y; xs[10]=xa2.z; xs[11]=xa2.w;
            xs[12]=xa3.x; xs[13]=xa3.y; xs[14]=xa3.z; xs[15]=xa3.w;

            const float* wrow = Wk + kc * 16 * 64;
#pragma unroll
            for (int i = 0; i < 16; ++i) {
                const float xi = xs[i];
                const float* wr = wrow + i * 64;   // wave-uniform -> s_load
#pragma unroll
                for (int c = 0; c < 64; ++c)
                    acc[c] = fmaf(xi, wr[c], acc[c]);
            }
            xa0 = xb0; xa1 = xb1; xa2 = xb2; xa3 = xb3;
        }

        // scatter: transpose 16 channels at a time through LDS, then atomics
        // (same-wave LDS ops are in-order; no barrier needed, slices private)
#pragma unroll
        for (int cc = 0; cc < 4; ++cc) {
#pragma unroll
            for (int q = 0; q < 4; ++q) {
                float4 v;
                v.x = acc[cc * 16 + q * 4 + 0];
                v.y = acc[cc * 16 + q * 4 + 1];
                v.z = acc[cc * 16 + q * 4 + 2];
                v.w = acc[cc * 16 + q * 4 + 3];
                *(float4*)&lds_t[wv][lane][q * 4] = v;
            }
            const int c16 = lane & 15;
#pragma unroll
            for (int t = 0; t < 16; ++t) {
                const int rr = (lane >> 4) + 4 * t;
                const float v = lds_t[wv][rr][c16];
                const int   d = lds_dst[wv][rr];
                atomicAdd(outp + (size_t)d * 64 + cc * 16 + c16, v);
            }
        }
    }
}

// Per-channel sum/sumsq; LDS reduce across the block's 4 waves, then atomics.
__global__ __launch_bounds__(256) void stats_kernel(
    const float* __restrict__ x, int nrows, float* __restrict__ stats)
{
    __shared__ float sh[2][4][64];
    const int c  = threadIdx.x & 63;
    const int rw = threadIdx.x >> 6;
    float s = 0.f, s2 = 0.f;
    for (int r = blockIdx.x * 4 + rw; r < nrows; r += gridDim.x * 4) {
        float v = x[(size_t)r * 64 + c];
        s += v;
        s2 = fmaf(v, v, s2);
    }
    sh[0][rw][c] = s;
    sh[1][rw][c] = s2;
    __syncthreads();
    if (rw == 0) {
        s  = (sh[0][0][c] + sh[0][1][c]) + (sh[0][2][c] + sh[0][3][c]);
        s2 = (sh[1][0][c] + sh[1][1][c]) + (sh[1][2][c] + sh[1][3][c]);
        atomicAdd(stats + c, s);
        atomicAdd(stats + 64 + c, s2);
    }
}

// stats[128+c]=mean, stats[192+c]=rsqrt(var+eps)
__global__ void finalize_stats(float* stats, float inv_n)
{
    const int c = threadIdx.x;   // 64 threads
    float mu  = stats[c] * inv_n;
    float var = stats[64 + c] * inv_n - mu * mu;
    stats[128 + c] = mu;
    stats[192 + c] = rsqrtf(var + EPSV);
}

// x = elu((x-mu)*scale) (+ fp32 encoder skip if enc != null), in place.
__global__ __launch_bounds__(256) void norm_elu(
    float* __restrict__ x, const float* __restrict__ stats,
    const float* __restrict__ enc)
{
    const int i = blockIdx.x * 256 + threadIdx.x;
    const int c = i & 63;
    float v = (x[i] - stats[128 + c]) * stats[192 + c];
    v = (v > 0.f) ? v : expm1f(v);
    if (enc) v += enc[i];
    x[i] = v;
}

// Final: normalize+elu, pruning dot, keep mask, fp32 outputs.
__global__ __launch_bounds__(256) void final_kernel(
    const float* __restrict__ x, const float* __restrict__ stats,
    const float* __restrict__ Wp, const float* __restrict__ bp,
    float* __restrict__ outp)
{
    const int lane = threadIdx.x & 63;
    const int wid  = threadIdx.x >> 6;
    const int row  = blockIdx.x * 4 + wid;

    float v = (x[(size_t)row * 64 + lane] - stats[128 + lane]) * stats[192 + lane];
    v = (v > 0.f) ? v : expm1f(v);

    float p = v * Wp[lane];
#pragma unroll
    for (int m = 1; m < 64; m <<= 1)
        p += __shfl_xor(p, m, 64);
    p += bp[0];

    const bool keep = p > 0.0f;
    outp[(size_t)row * 64 + lane] = keep ? v : 0.f;
    if (lane == 0)
        outp[(size_t)N_OUT * 64 + row] = keep ? 1.f : 0.f;
}

extern "C" void kernel_launch(void* const* d_in, const int* in_sizes, int n_in,
                              void* d_out, int out_size, void* d_ws, size_t ws_size,
                              hipStream_t stream)
{
    const float* in_feats = (const float*)d_in[0];   // [65536,128] f32
    const float* enc      = (const float*)d_in[1];   // [262144,64] f32
    const float* W1       = (const float*)d_in[2];   // [27,128,64] f32
    const float* W2       = (const float*)d_in[3];   // [27,64,64]  f32
    const float* W3       = (const float*)d_in[4];   // [16,64,64]  f32
    const float* Wp       = (const float*)d_in[5];   // [64,1] f32
    const float* bp       = (const float*)d_in[6];   // [1] f32
    const int* kin1  = (const int*)d_in[7];
    const int* kout1 = (const int*)d_in[8];
    const int* kin2  = (const int*)d_in[9];
    const int* kout2 = (const int*)d_in[10];
    const int* kin3  = (const int*)d_in[11];
    const int* kout3 = (const int*)d_in[12];
    float* outp = (float*)d_out;

    char* ws = (char*)d_ws;
    float* up_a   = (float*)ws;                         // 64 MB  [262144,64] f32
    float* up_b   = (float*)(ws + 67108864);            // 64 MB  [262144,64] f32
    float* out3   = up_a;                               // 32 MB reuse after conv2
    float* statsA = (float*)(ws + 134217728);           // 256 f32 each
    float* statsB = statsA + 256;
    float* statsC = statsA + 512;

    hipMemsetAsync(up_a, 0, (size_t)N_UP * 64 * 4, stream);
    hipMemsetAsync(up_b, 0, (size_t)N_UP * 64 * 4, stream);
    hipMemsetAsync(statsA, 0, 3 * 256 * 4, stream);

    // ---- dec_block_1a: conv-transpose (gather input_feats, scatter to up_a)
    conv_gemm<128, 16><<<(K1 * WPK) / 4, 256, 0, stream>>>(
        in_feats, W1, kin1, kout1, up_a);
    stats_kernel<<<512, 256, 0, stream>>>(up_a, N_UP, statsA);
    finalize_stats<<<1, 64, 0, stream>>>(statsA, 1.f / N_UP);
    norm_elu<<<(N_UP * 64) / 256, 256, 0, stream>>>(up_a, statsA, nullptr);

    // ---- dec_block_1b: conv 3x3x3 (up_a -> up_b)
    conv_gemm<64, 17><<<(K2 * WPK) / 4, 256, 0, stream>>>(
        up_a, W2, kin2, kout2, up_b);
    stats_kernel<<<512, 256, 0, stream>>>(up_b, N_UP, statsB);
    finalize_stats<<<1, 64, 0, stream>>>(statsB, 1.f / N_UP);
    norm_elu<<<(N_UP * 64) / 256, 256, 0, stream>>>(up_b, statsB, enc);  // + skip

    // ---- dec_block_2: conv k=2 (up_b -> out3), out3 reuses up_a storage
    hipMemsetAsync(out3, 0, (size_t)N_OUT * 64 * 4, stream);
    conv_gemm<64, 17><<<(K3 * WPK) / 4, 256, 0, stream>>>(
        up_b, W3, kin3, kout3, out3);
    stats_kernel<<<512, 256, 0, stream>>>(out3, N_OUT, statsC);
    finalize_stats<<<1, 64, 0, stream>>>(statsC, 1.f / N_OUT);

    // ---- pruning head + fp32 outputs
    final_kernel<<<N_OUT / 4, 256, 0, stream>>>(out3, statsC, Wp, bp, outp);
}